// Round 1
// baseline (808.852 us; speedup 1.0000x reference)
//
#include <hip/hip_runtime.h>
#include <hip/hip_bf16.h>

// Problem constants (from reference):
// B, L, V, D, NCTX, DEPTH, VD = (4096, 77, 49408, 512, 4, 9, 768)
#define BB   4096
#define LL   77
#define DD   512
#define NCTX 4
#define KK   8          // DEPTH - 1
#define VD   768

// Output layout (flat f32 element offsets, concatenated in return order):
// pe (B,L,D) | pt (B,L) | ctx (4,512) | proj_ctx (4,768) | cpt (8,4,512) | vdp (8,4,768)
#define OFF_PE   0L
#define OFF_PT   161480704L   // B*L*D
#define OFF_CTX  161796096L   // + B*L
#define OFF_PROJ 161798144L   // + 2048
#define OFF_CPT  161801216L   // + 3072
#define OFF_VDP  161817600L   // + 16384

// ---------------------------------------------------------------------------
// Kernel 1: build pt (one wave64 per row of B rows).
//   pt[0]   = text[0]
//   pt[1..4]= 0
//   pt[p]   = text[p-4]           for p in [5,75]
//   pt[76]  = text[72]!=0 ? rowmax(text) : 0
// Written as f32 straight into the output's pt slice (exact: tokens < 2^24).
// ---------------------------------------------------------------------------
__global__ __launch_bounds__(256) void k_build_pt(const int* __restrict__ text,
                                                  float* __restrict__ pt_f) {
    int gid  = blockIdx.x * 256 + threadIdx.x;
    int row  = gid >> 6;          // [0, B)
    int lane = gid & 63;
    const int* t = text + row * LL;

    const int NEG = -2147483647 - 1;
    int v0 = (lane < LL)      ? t[lane]      : NEG;
    int v1 = (lane + 64 < LL) ? t[lane + 64] : NEG;
    int m  = v0 > v1 ? v0 : v1;
    #pragma unroll
    for (int off = 32; off; off >>= 1) {
        int o = __shfl_xor(m, off);
        m = o > m ? o : m;
    }
    // m == row max == eot token

    float* dst = pt_f + (long)row * LL;
    #pragma unroll
    for (int pass = 0; pass < 2; ++pass) {
        int pos = lane + pass * 64;
        if (pos < LL) {
            int v;
            if (pos == 0)        v = t[0];
            else if (pos <= NCTX) v = 0;
            else if (pos == LL - 1) { int x = t[LL - 5]; v = (x != 0) ? m : 0; }
            else                 v = t[pos - NCTX];
            dst[pos] = (float)v;
        }
    }
}

// ---------------------------------------------------------------------------
// Kernel 2: pe gather. One float4 (16 B) per thread; B*L*128 threads.
//   pos in [1,4] -> ctx[pos-1], else -> emb[(int)pt[row]].
// ---------------------------------------------------------------------------
__global__ __launch_bounds__(256) void k_gather_pe(const float4* __restrict__ emb,
                                                   const float4* __restrict__ ctx,
                                                   const float* __restrict__ pt_f,
                                                   float4* __restrict__ pe) {
    int t   = blockIdx.x * 256 + threadIdx.x;   // [0, B*L*128)
    int row = t >> 7;                           // (b,pos) flat
    int c   = t & 127;
    int pos = row % LL;                         // magic-div by compiler

    const float4* src;
    if (pos >= 1 && pos <= NCTX) {
        src = ctx + (pos - 1) * (DD / 4);
    } else {
        int tok = (int)pt_f[row];
        src = emb + (long)tok * (DD / 4);
    }
    pe[t] = src[c];
}

// ---------------------------------------------------------------------------
// Kernel 3: small dot products, one wave64 per output element.
//   waves [0, 3072):       proj_ctx[n][o] = dot(ctx[n], proj_w[o]) + proj_b[o]
//   waves [3072, 27648):   vdp[k][n][o]   = dot(cpt[k][n], cw[k][o]) + cb[k][o]
// Each lane: 8 contiguous floats (2x float4), then shuffle tree reduce.
// ---------------------------------------------------------------------------
__global__ __launch_bounds__(256) void k_small_dots(const float* __restrict__ ctx,
                                                    const float* __restrict__ proj_w,
                                                    const float* __restrict__ proj_b,
                                                    const float* __restrict__ cpt,
                                                    const float* __restrict__ cw,
                                                    const float* __restrict__ cb,
                                                    float* __restrict__ out) {
    int gid  = blockIdx.x * 256 + threadIdx.x;
    int wave = gid >> 6;
    int lane = gid & 63;

    const float* a;
    const float* b;
    float bias;
    float* dst;

    if (wave < NCTX * VD) {
        int n = wave / VD;
        int o = wave - n * VD;
        a    = ctx + n * DD;
        b    = proj_w + (long)o * DD;
        bias = proj_b[o];
        dst  = out + OFF_PROJ + wave;
    } else {
        int w = wave - NCTX * VD;
        int k = w / (NCTX * VD);
        int r = w - k * (NCTX * VD);
        int n = r / VD;
        int o = r - n * VD;
        a    = cpt + (long)(k * NCTX + n) * DD;
        b    = cw + (long)(k * VD + o) * DD;
        bias = cb[k * VD + o];
        dst  = out + OFF_VDP + w;
    }

    const float4* a4 = (const float4*)a + lane * 2;
    const float4* b4 = (const float4*)b + lane * 2;
    float4 x0 = a4[0], x1 = a4[1];
    float4 y0 = b4[0], y1 = b4[1];
    float s = x0.x * y0.x + x0.y * y0.y + x0.z * y0.z + x0.w * y0.w
            + x1.x * y1.x + x1.y * y1.y + x1.z * y1.z + x1.w * y1.w;
    #pragma unroll
    for (int off = 32; off; off >>= 1) s += __shfl_xor(s, off);
    if (lane == 0) *dst = s + bias;
}

extern "C" void kernel_launch(void* const* d_in, const int* in_sizes, int n_in,
                              void* d_out, int out_size, void* d_ws, size_t ws_size,
                              hipStream_t stream) {
    const int*   text   = (const int*)d_in[0];
    const float* emb    = (const float*)d_in[1];
    const float* ctx    = (const float*)d_in[2];
    const float* proj_w = (const float*)d_in[3];
    const float* proj_b = (const float*)d_in[4];
    const float* cpt    = (const float*)d_in[5];
    const float* cw     = (const float*)d_in[6];
    const float* cb     = (const float*)d_in[7];
    float* out = (float*)d_out;

    // 1) pt  (must precede the gather, which reads it)
    {
        int waves  = BB;                       // one wave per row
        int blocks = waves * 64 / 256;         // 1024
        k_build_pt<<<blocks, 256, 0, stream>>>(text, out + OFF_PT);
    }

    // 2) pe gather: B*L*128 float4-threads
    {
        long threads = (long)BB * LL * 128;    // 40,370,176 (exact /256)
        int  blocks  = (int)(threads / 256);   // 157,696
        k_gather_pe<<<blocks, 256, 0, stream>>>((const float4*)emb,
                                                (const float4*)ctx,
                                                out + OFF_PT,
                                                (float4*)(out + OFF_PE));
    }

    // 3) small GEMMs: 27648 waves, 4 waves/block
    {
        int waves  = NCTX * VD + KK * NCTX * VD;   // 3072 + 24576
        int blocks = waves * 64 / 256;             // 6912
        k_small_dots<<<blocks, 256, 0, stream>>>(ctx, proj_w, proj_b,
                                                 cpt, cw, cb, out);
    }

    // 4) pass-through copies (async D2D is graph-capture safe)
    hipMemcpyAsync(out + OFF_CTX, ctx, (size_t)NCTX * DD * sizeof(float),
                   hipMemcpyDeviceToDevice, stream);
    hipMemcpyAsync(out + OFF_CPT, cpt, (size_t)KK * NCTX * DD * sizeof(float),
                   hipMemcpyDeviceToDevice, stream);
}

// Round 3
// 758.760 us; speedup vs baseline: 1.0660x; 1.0660x over previous
//
#include <hip/hip_runtime.h>
#include <hip/hip_bf16.h>

// B, L, V, D, NCTX, DEPTH, VD = (4096, 77, 49408, 512, 4, 9, 768)
#define BB   4096
#define LL   77
#define DD   512
#define NCTX 4
#define KK   8          // DEPTH - 1
#define VD   768

// Output layout (flat f32 element offsets, concatenated in return order):
// pe (B,L,D) | pt (B,L) | ctx (4,512) | proj_ctx (4,768) | cpt (8,4,512) | vdp (8,4,768)
#define OFF_PE   0L
#define OFF_PT   161480704L   // B*L*D
#define OFF_CTX  161796096L   // + B*L
#define OFF_PROJ 161798144L   // + 2048
#define OFF_CPT  161801216L   // + 3072
#define OFF_VDP  161817600L   // + 16384

typedef float f32x4 __attribute__((ext_vector_type(4)));

// Block-range partition of the prep kernel
#define DOT_BLOCKS 6912       // 27648 waves, one output elem each
#define PT_BLOCKS  1024       // 4096 waves, one text row each
#define CPY_BLOCKS 18         // 4608 float4 (ctx 512 + cpt 4096)

// ---------------------------------------------------------------------------
// Prep kernel: small dots + pt build + pass-through copies, fused by block id.
// ---------------------------------------------------------------------------
__global__ __launch_bounds__(256) void k_prep(const int* __restrict__ text,
                                              const float* __restrict__ ctx,
                                              const float* __restrict__ proj_w,
                                              const float* __restrict__ proj_b,
                                              const float* __restrict__ cpt,
                                              const float* __restrict__ cw,
                                              const float* __restrict__ cb,
                                              float* __restrict__ out) {
    int blk = blockIdx.x;
    int tid = threadIdx.x;

    if (blk < DOT_BLOCKS) {
        // ---- small dot products: one wave64 per output element ----
        int gid  = blk * 256 + tid;
        int wave = gid >> 6;
        int lane = gid & 63;

        const float* a;
        const float* b;
        float bias;
        float* dst;

        if (wave < NCTX * VD) {
            int n = wave / VD;
            int o = wave - n * VD;
            a    = ctx + n * DD;
            b    = proj_w + (long)o * DD;
            bias = proj_b[o];
            dst  = out + OFF_PROJ + wave;
        } else {
            int w = wave - NCTX * VD;
            int k = w / (NCTX * VD);
            int r = w - k * (NCTX * VD);
            int n = r / VD;
            int o = r - n * VD;
            a    = cpt + (long)(k * NCTX + n) * DD;
            b    = cw + (long)(k * VD + o) * DD;
            bias = cb[k * VD + o];
            dst  = out + OFF_VDP + w;
        }

        const f32x4* a4 = (const f32x4*)a + lane * 2;
        const f32x4* b4 = (const f32x4*)b + lane * 2;
        f32x4 x0 = a4[0], x1 = a4[1];
        f32x4 y0 = b4[0], y1 = b4[1];
        float s = x0.x * y0.x + x0.y * y0.y + x0.z * y0.z + x0.w * y0.w
                + x1.x * y1.x + x1.y * y1.y + x1.z * y1.z + x1.w * y1.w;
        #pragma unroll
        for (int off = 32; off; off >>= 1) s += __shfl_xor(s, off);
        if (lane == 0) *dst = s + bias;

    } else if (blk < DOT_BLOCKS + PT_BLOCKS) {
        // ---- build pt: one wave64 per text row ----
        int gid  = (blk - DOT_BLOCKS) * 256 + tid;
        int row  = gid >> 6;
        int lane = gid & 63;
        const int* t = text + row * LL;

        const int NEG = -2147483647 - 1;
        int v0 = (lane < LL)      ? t[lane]      : NEG;
        int v1 = (lane + 64 < LL) ? t[lane + 64] : NEG;
        int m  = v0 > v1 ? v0 : v1;
        #pragma unroll
        for (int off = 32; off; off >>= 1) {
            int o = __shfl_xor(m, off);
            m = o > m ? o : m;
        }
        // m == row max == eot token

        float* dst = out + OFF_PT + (long)row * LL;
        #pragma unroll
        for (int pass = 0; pass < 2; ++pass) {
            int pos = lane + pass * 64;
            if (pos < LL) {
                int v;
                if (pos == 0)          v = t[0];
                else if (pos <= NCTX)  v = 0;
                else if (pos == LL - 1){ int x = t[LL - 5]; v = (x != 0) ? m : 0; }
                else                   v = t[pos - NCTX];
                dst[pos] = (float)v;
            }
        }

    } else {
        // ---- pass-through copies: ctx (512 f4) then cpt (4096 f4) ----
        int i = (blk - DOT_BLOCKS - PT_BLOCKS) * 256 + tid;   // [0, 4608)
        const f32x4* c4  = (const f32x4*)ctx;
        const f32x4* p4  = (const f32x4*)cpt;
        f32x4* o4 = (f32x4*)out;
        if (i < 512) {
            o4[OFF_CTX / 4 + i] = c4[i];
        } else {
            o4[OFF_CPT / 4 + (i - 512)] = p4[i - 512];
        }
    }
}

// ---------------------------------------------------------------------------
// Gather kernel: one wave64 per (b,pos) row; 32 B/lane; nontemporal pe stores
// so the 101 MB emb table stays resident in Infinity Cache.
// ---------------------------------------------------------------------------
__global__ __launch_bounds__(256) void k_gather(const f32x4* __restrict__ emb,
                                                const f32x4* __restrict__ ctx,
                                                const float* __restrict__ pt_f,
                                                f32x4* __restrict__ pe) {
    int t    = blockIdx.x * 256 + threadIdx.x;   // [0, B*L*64)
    int row  = t >> 6;                           // (b,pos) flat
    int lane = t & 63;
    int pos  = row % LL;

    const f32x4* src;
    if (pos >= 1 && pos <= NCTX) {
        src = ctx + (pos - 1) * (DD / 4);
    } else {
        int tok = (int)pt_f[row];
        src = emb + (long)tok * (DD / 4);
    }
    f32x4 a = src[lane];
    f32x4 b = src[lane + 64];
    f32x4* dst = pe + (long)row * (DD / 4);
    __builtin_nontemporal_store(a, dst + lane);
    __builtin_nontemporal_store(b, dst + lane + 64);
}

extern "C" void kernel_launch(void* const* d_in, const int* in_sizes, int n_in,
                              void* d_out, int out_size, void* d_ws, size_t ws_size,
                              hipStream_t stream) {
    const int*   text   = (const int*)d_in[0];
    const float* emb    = (const float*)d_in[1];
    const float* ctx    = (const float*)d_in[2];
    const float* proj_w = (const float*)d_in[3];
    const float* proj_b = (const float*)d_in[4];
    const float* cpt    = (const float*)d_in[5];
    const float* cw     = (const float*)d_in[6];
    const float* cb     = (const float*)d_in[7];
    float* out = (float*)d_out;

    // 1) prep: small dots + pt + copies (pt must precede the gather)
    k_prep<<<DOT_BLOCKS + PT_BLOCKS + CPY_BLOCKS, 256, 0, stream>>>(
        text, ctx, proj_w, proj_b, cpt, cw, cb, out);

    // 2) pe gather: one wave per row, 32 B per lane
    {
        long threads = (long)BB * LL * 64;    // 20,185,088 (exact /256)
        int  blocks  = (int)(threads / 256);  // 78,848
        k_gather<<<blocks, 256, 0, stream>>>((const f32x4*)emb,
                                             (const f32x4*)ctx,
                                             out + OFF_PT,
                                             (f32x4*)(out + OFF_PE));
    }
}